// Round 13
// baseline (49.548 us; speedup 1.0000x reference)
//
#include <hip/hip_runtime.h>
#include <hip/hip_bf16.h>
#include <stdint.h>

// PWB linear layer: out = relu(x @ q(W) + q(b)), q = round(clip(t,-1,1)*127)/127
// R13: GEMM VERBATIM R8 (best: B-from-global L2-resident, LDS-A 4x8KB,
// 2 blocks/CU). Prep split & fixed:
//   pwb_prep_x: 1 block per 16-row block-row, 16x2048 f32 staged in 128KB LDS
//     (single coalesced HBM read), per-wave rowmax reduce, quantize from LDS,
//     stores 256B/wave contiguous into tiled xq (was 4B-scattered = 1/4 eff).
//   pwb_prep_w: R11's coalesced W-path (LDS-transpose [64][80], 8B/lane
//     contiguous 1KB-per-n-block stores).
// Layouts: xq[M/16][K/64][16][64] i8, Wq[N/16][K/64][16][64] i8.

typedef __attribute__((ext_vector_type(4))) int i32x4;

#define BM 128
#define BN 128
#define BK 64

__device__ __forceinline__ float pwb_clip(float w) {
    return fminf(fmaxf(w, -1.f), 1.f);
}

__device__ __forceinline__ void gl16(const int8_t* g, int8_t* l) {
    __builtin_amdgcn_global_load_lds(
        (const __attribute__((address_space(1))) void*)(g),
        (__attribute__((address_space(3))) void*)(l),
        16, 0, 0);
}

#define WAIT_VM6   asm volatile("s_waitcnt vmcnt(6)" ::: "memory");
#define WAIT_VM4   asm volatile("s_waitcnt vmcnt(4)" ::: "memory");
#define WAIT_VM2   asm volatile("s_waitcnt vmcnt(2)" ::: "memory");
#define WAIT_VM0   asm volatile("s_waitcnt vmcnt(0)" ::: "memory");
#define BAR()      __builtin_amdgcn_s_barrier();

// ---- x pre-pass: 16 rows per block, LDS-staged, coalesced in and out ----
__global__ __launch_bounds__(512) void pwb_prep_x(
        const float* __restrict__ x, int8_t* __restrict__ xq,
        float* __restrict__ scales, int DIN) {
    __shared__ __align__(16) float xs[16 * 2048];    // 128KB (DIN<=2048 gated)
    __shared__ float wmax[16][8];
    __shared__ float sc[16];
    const int t  = threadIdx.x;
    const int wv = t >> 6, l = t & 63;
    const int row16 = blockIdx.x;
    const size_t KB = (size_t)(DIN >> 6) << 10;      // bytes per block-row
    const float* xb = x + (size_t)row16 * 16 * DIN;
    const int J = DIN >> 7;                          // 2048-float chunks

    if (t < 128) wmax[t >> 3][t & 7] = 0.f;
    __syncthreads();

    // phase A: stream 16 rows into LDS (fully coalesced), per-wave rowmax
    for (int j = 0; j < J; ++j) {
        const int base = j * 2048 + t * 4;           // wave spans 256 floats (1 row)
        float4 v = *(const float4*)(xb + base);
        *(float4*)&xs[base] = v;
        float m = fmaxf(fmaxf(fabsf(v.x), fabsf(v.y)),
                        fmaxf(fabsf(v.z), fabsf(v.w)));
#pragma unroll
        for (int d = 1; d < 64; d <<= 1) m = fmaxf(m, __shfl_xor(m, d));
        if (l == 0) {
            const int rloc = (j * 2048 + wv * 256) / DIN;
            wmax[rloc][wv] = fmaxf(wmax[rloc][wv], m);
        }
    }
    __syncthreads();
    if (t < 16) {
        float m = 0.f;
#pragma unroll
        for (int i = 0; i < 8; ++i) m = fmaxf(m, wmax[t][i]);
        scales[row16 * 16 + t] = m / 16129.f;        // rowmax / 127^2
        sc[t] = (m > 0.f) ? 127.f / m : 0.f;
    }
    __syncthreads();

    // phase B: quantize from LDS; thread t -> byte-quad q of k-tile 2*it+half.
    // global stores: 256B/wave contiguous (1KB per 4 waves per tile).
    const int half = t >> 8, q = t & 255;
    const int pr = q >> 4, pw = q & 15;
    const float rr = sc[pr];
    int8_t* xo = xq + (size_t)row16 * KB;
    for (int it = 0; it < J; ++it) {
        const int kt = it * 2 + half;
        float4 v = *(const float4*)&xs[pr * DIN + kt * 64 + pw * 4];
        int q0 = (int)rintf(v.x * rr), q1 = (int)rintf(v.y * rr);
        int q2 = (int)rintf(v.z * rr), q3 = (int)rintf(v.w * rr);
        uint32_t u = (uint32_t)(q0 & 255) | ((uint32_t)(q1 & 255) << 8) |
                     ((uint32_t)(q2 & 255) << 16) | ((uint32_t)(q3 & 255) << 24);
        *(uint32_t*)(xo + (size_t)kt * 1024 + q * 4) = u;
    }
}

// ---- W pre-pass: 64x64 tile, LDS-transposed, coalesced stores ----
__global__ __launch_bounds__(512) void pwb_prep_w(
        const float* __restrict__ W, int8_t* __restrict__ Wq,
        int DIN, int DOUT) {
    __shared__ __align__(16) int8_t tq[64 * 80];     // [64 n][80 k] i8
    const int t = threadIdx.x;
    const size_t KB = (size_t)(DIN >> 6) << 10;
    const int gw = DOUT >> 6;
    const int c0 = ((int)blockIdx.x % gw) * 64;      // n base
    const int r0 = ((int)blockIdx.x / gw) * 64;      // k base
    const int nc = (t & 15) * 4;
#pragma unroll
    for (int it = 0; it < 2; ++it) {
        const int kl = it * 32 + (t >> 4);           // k-local 0..63
        float4 wv = *(const float4*)&W[(size_t)(r0 + kl) * DOUT + c0 + nc];
        tq[(nc + 0) * 80 + kl] = (int8_t)rintf(pwb_clip(wv.x) * 127.f);
        tq[(nc + 1) * 80 + kl] = (int8_t)rintf(pwb_clip(wv.y) * 127.f);
        tq[(nc + 2) * 80 + kl] = (int8_t)rintf(pwb_clip(wv.z) * 127.f);
        tq[(nc + 3) * 80 + kl] = (int8_t)rintf(pwb_clip(wv.w) * 127.f);
    }
    __syncthreads();
    // nb = t>>7 (16-row n-block), q = t&127 -> 8B at tile byte 8q (contiguous 1KB/nb)
    const int nb = t >> 7, q = t & 127;
    const int nloc = nb * 16 + (q >> 3), w8 = q & 7;
    uint2 u = *(const uint2*)&tq[nloc * 80 + w8 * 8];
    *(uint2*)(Wq + (size_t)((c0 >> 4) + nb) * KB +
              (size_t)(r0 >> 6) * 1024 + q * 8) = u;
}

// ================= main GEMM (i8, B from global) — VERBATIM R8 =================
// C[M][N] = relu( (A x B^T) * scales[row] + q(b)[col] )
__global__ __launch_bounds__(256, 2) void pwb_gemmq(
    const int8_t* __restrict__ A,    // xq tiled [M/16][K/64][16][64]
    const int8_t* __restrict__ Bt,   // Wq tiled [N/16][K/64][16][64]
    const float* __restrict__ scales,// [M] rowmax/127^2
    const float* __restrict__ b,     // [N] raw bias (quantized inline)
    float* __restrict__ C,           // [M][N] f32
    int M, int N, int K, int GN, int nwg) {
    __shared__ __align__(16) int8_t lA[4][BM * BK];  // 4 x 8KB

    const int tid = threadIdx.x;
    const int w   = tid >> 6;     // 0..3
    const int l   = tid & 63;
    const int lr  = l & 15;
    const int lk  = l >> 4;       // 0..3

    // bijective XCD swizzle (m204)
    const int bid = blockIdx.x;
    const int q = nwg >> 3, r = nwg & 7;
    const int xcd = bid & 7, lin = bid >> 3;
    const int wgid = (xcd < r ? xcd * (q + 1) : r * (q + 1) + (xcd - r) * q) + lin;
    const int tm = wgid / GN, tn = wgid % GN;
    const size_t brow = (size_t)tm * BM, bcol = (size_t)tn * BN;

    const int wm = (w >> 1) * 64;   // wave M offset
    const int wn = (w & 1) * 64;    // wave N offset

    const int KT = K >> 6;                 // number of K-tiles
    const size_t KB = (size_t)KT << 10;    // bytes per 16-row block-row

    const int8_t* gA[2];
#pragma unroll
    for (int i = 0; i < 2; ++i) {
        int s = tid + 256 * i;
        gA[i] = A + (size_t)((brow >> 4) + (s >> 6)) * KB + (s & 63) * 16;
    }
    const int8_t* pB = Bt + (size_t)((bcol + wn) >> 4) * KB + lr * 64 + lk * 16;
    const int offA = (wm >> 4) * 1024 + lr * 64 + lk * 16;

    i32x4 acc[4][4] = {};
    i32x4 bS0[4], bS1[4], afr[4];

#define STAGE(buf, t)                                                   \
    gl16(gA[0] + (size_t)(t) * 1024, &lA[buf][tid * 16]);               \
    gl16(gA[1] + (size_t)(t) * 1024, &lA[buf][(tid + 256) * 16]);

#define LOADB(set, t)                                                   \
    _Pragma("unroll") for (int nj = 0; nj < 4; ++nj)                    \
        set[nj] = *(const i32x4*)(pB + (size_t)nj * KB + (size_t)(t) * 1024);

#define LOADA(buf)                                                      \
    _Pragma("unroll") for (int mi = 0; mi < 4; ++mi)                    \
        afr[mi] = *(const i32x4*)&lA[buf][offA + mi * 1024];

#define MFMA16(fb)                                                      \
    __builtin_amdgcn_s_setprio(1);                                      \
    _Pragma("unroll") for (int mi = 0; mi < 4; ++mi)                    \
    _Pragma("unroll") for (int nj = 0; nj < 4; ++nj)                    \
        acc[mi][nj] = __builtin_amdgcn_mfma_i32_16x16x64_i8(            \
            afr[mi], fb[nj], acc[mi][nj], 0, 0, 0);                     \
    __builtin_amdgcn_s_setprio(0);

    // ---- prologue: A0, B0, A1 in flight; wait A0+B0 ----
    STAGE(0, 0)
    LOADB(bS0, 0)
    STAGE(1, 1)
    WAIT_VM2
    BAR();

    const int T = KT;   // even, >= 4 (gated)
    for (int it = 0; it < (T - 2) / 2; ++it) {
        const int t0 = 2 * it;
        LOADB(bS1, t0 + 1)
        STAGE((t0 + 2) & 3, t0 + 2)
        LOADA(t0 & 3)
        WAIT_VM6            // retires B(t0) + A-stage(t0+1)
        BAR();
        MFMA16(bS0)
        LOADB(bS0, t0 + 2)
        STAGE((t0 + 3) & 3, t0 + 3)
        LOADA((t0 + 1) & 3)
        WAIT_VM6
        BAR();
        MFMA16(bS1)
    }
    // ---- tail: tiles T-2 (bS0), T-1 (bS1) ----
    LOADB(bS1, T - 1)
    LOADA((T - 2) & 3)
    WAIT_VM4                // retires B(T-2) + A-stage(T-1)
    BAR();
    MFMA16(bS0)
    WAIT_VM0                // B(T-1) in regs
    LOADA((T - 1) & 3)
    MFMA16(bS1)

    // ---- epilogue ----
    float bias[4];
#pragma unroll
    for (int nj = 0; nj < 4; ++nj) {
        float bv = b[bcol + wn + nj * 16 + lr];
        bias[nj] = rintf(pwb_clip(bv) * 127.f) * (1.f / 127.f);
    }

    const size_t orow = brow + wm + lk * 4;   // multiple of 4
    const size_t ocol = bcol + wn + lr;
    float4 scl[4];
#pragma unroll
    for (int mi = 0; mi < 4; ++mi)
        scl[mi] = *(const float4*)&scales[orow + mi * 16];

#pragma unroll
    for (int mi = 0; mi < 4; ++mi) {
        const float s0_ = scl[mi].x, s1_ = scl[mi].y, s2_ = scl[mi].z, s3_ = scl[mi].w;
#pragma unroll
        for (int nj = 0; nj < 4; ++nj) {
            float v0 = fmaf((float)acc[mi][nj][0], s0_, bias[nj]);
            float v1 = fmaf((float)acc[mi][nj][1], s1_, bias[nj]);
            float v2 = fmaf((float)acc[mi][nj][2], s2_, bias[nj]);
            float v3 = fmaf((float)acc[mi][nj][3], s3_, bias[nj]);
            float* cp = &C[(orow + mi * 16) * N + (ocol + nj * 16)];
            cp[0 * N] = fmaxf(v0, 0.f);
            cp[1 * N] = fmaxf(v1, 0.f);
            cp[2 * N] = fmaxf(v2, 0.f);
            cp[3 * N] = fmaxf(v3, 0.f);
        }
    }
#undef STAGE
#undef LOADB
#undef LOADA
#undef MFMA16
}

// ---- fallback (any shape): fp32, on-the-fly quantize ----
__global__ void pwb_fallback(const float* __restrict__ x, const float* __restrict__ W,
                             const float* __restrict__ b, float* __restrict__ out,
                             int M, int N, int K) {
    __shared__ float sA[16][17];
    __shared__ float sB[16][17];
    int tx = threadIdx.x, ty = threadIdx.y;
    int row = blockIdx.y * 16 + ty;
    int col = blockIdx.x * 16 + tx;
    float acc = 0.f;
    for (int kt = 0; kt < K; kt += 16) {
        sA[ty][tx] = (row < M && kt + tx < K) ? x[(size_t)row * K + kt + tx] : 0.f;
        float w = (kt + ty < K && col < N) ? W[(size_t)(kt + ty) * N + col] : 0.f;
        sB[ty][tx] = rintf(pwb_clip(w) * 127.f) * (1.f / 127.f);
        __syncthreads();
#pragma unroll
        for (int kk = 0; kk < 16; ++kk) acc += sA[ty][kk] * sB[kk][tx];
        __syncthreads();
    }
    if (row < M && col < N) {
        float v = acc + rintf(pwb_clip(b[col]) * 127.f) * (1.f / 127.f);
        out[(size_t)row * N + col] = fmaxf(v, 0.f);
    }
}

extern "C" void kernel_launch(void* const* d_in, const int* in_sizes, int n_in,
                              void* d_out, int out_size, void* d_ws, size_t ws_size,
                              hipStream_t stream) {
    const float* x = (const float*)d_in[0];
    const float* W = (const float*)d_in[1];
    const float* b = (const float*)d_in[2];
    float* out = (float*)d_out;

    const int DOUT = in_sizes[2];
    const int DIN  = in_sizes[1] / DOUT;
    const int M    = in_sizes[0] / DIN;

    size_t need = (size_t)M * DIN + (size_t)DIN * DOUT + (size_t)M * 4;
    const int T = DIN / 64;
    bool fast = (M % BM == 0) && (M % 16 == 0) && (DOUT % BN == 0) &&
                (DIN % 256 == 0) && (DIN <= 2048) && (T >= 4) && ((T & 1) == 0) &&
                (ws_size >= need);

    if (fast) {
        int8_t* xq = (int8_t*)d_ws;                       // tiled [M/16][K/64][16][64]
        int8_t* Wq = xq + (size_t)M * DIN;                // tiled [N/16][K/64][16][64]
        float* scales = (float*)(Wq + (size_t)DIN * DOUT);// [M] f32

        pwb_prep_x<<<M / 16, 512, 0, stream>>>(x, xq, scales, DIN);
        pwb_prep_w<<<(DIN / 64) * (DOUT / 64), 512, 0, stream>>>(W, Wq, DIN, DOUT);

        const int GM = M / BM, GN = DOUT / BN, nwg = GM * GN;
        pwb_gemmq<<<nwg, 256, 0, stream>>>(xq, Wq, scales, b, out, M, DOUT, DIN, GN, nwg);
    } else {
        dim3 g((DOUT + 15) / 16, (M + 15) / 16), blk(16, 16);
        pwb_fallback<<<g, blk, 0, stream>>>(x, W, b, out, M, DOUT, DIN);
    }
}

// Round 14
// 40.479 us; speedup vs baseline: 1.2240x; 1.2240x over previous
//
#include <hip/hip_runtime.h>
#include <hip/hip_bf16.h>
#include <stdint.h>

// PWB linear layer: out = relu(x @ q(W) + q(b)), q = round(clip(t,-1,1)*127)/127
// R14: EXACTLY R8 (best measured, 40.5us) + ONE change: XOR bank-swizzle on
// the A LDS tile. R8's linear tiled A-read (lr*64+lk*16) is an ~8-way bank
// conflict (rows lr, lr+2 share bank quads). Fix (both-sides, m231 rule):
//   stage: LDS dest linear; GLOBAL source chunk pre-permuted sl^((rr>>1)&3)
//   read:  slot lk^((lr>>1)&3)  -> each 8-row stripe covers all 32 banks,
//          2-way max aliasing (free per m136). R6 profiled this pattern at
//          SQ_LDS_BANK_CONFLICT=0.
// Layouts: xq[M/16][K/64][16][64] i8, Wq[N/16][K/64][16][64] i8.

typedef __attribute__((ext_vector_type(4))) int i32x4;

#define BM 128
#define BN 128
#define BK 64

__device__ __forceinline__ float pwb_clip(float w) {
    return fminf(fmaxf(w, -1.f), 1.f);
}

__device__ __forceinline__ void gl16(const int8_t* g, int8_t* l) {
    __builtin_amdgcn_global_load_lds(
        (const __attribute__((address_space(1))) void*)(g),
        (__attribute__((address_space(3))) void*)(l),
        16, 0, 0);
}

#define WAIT_VM6   asm volatile("s_waitcnt vmcnt(6)" ::: "memory");
#define WAIT_VM4   asm volatile("s_waitcnt vmcnt(4)" ::: "memory");
#define WAIT_VM2   asm volatile("s_waitcnt vmcnt(2)" ::: "memory");
#define WAIT_VM0   asm volatile("s_waitcnt vmcnt(0)" ::: "memory");
#define BAR()      __builtin_amdgcn_s_barrier();

// ---- merged pre-pass (verbatim R8) ----
// blocks [0,xblocks): x rows -> per-row i8 (LDS-staged single HBM read), tiled
// blocks [xblocks,..): W 64x64 tiles -> quantize+transpose, tiled Wq
__global__ void pwb_prep(const float* __restrict__ x, const float* __restrict__ W,
                         int8_t* __restrict__ xq, int8_t* __restrict__ Wq,
                         float* __restrict__ scales, int DIN, int DOUT, int xblocks) {
    __shared__ __align__(16) float smem[4 * 2048];   // 32KB
    const int tid = threadIdx.x;
    const size_t KB = (size_t)(DIN >> 6) << 10;      // bytes per 16-row block-row

    if ((int)blockIdx.x < xblocks) {
        // ---- x path: one wave per row; stage row in LDS, quantize from LDS ----
        const int wv = tid >> 6, l = tid & 63;
        const int row = blockIdx.x * 4 + wv;
        const float4* xr = (const float4*)(x + (size_t)row * DIN);
        float* xs = smem + wv * 2048;
        const int J = DIN >> 8;                      // float4 groups per lane
        float m = 0.f;
        for (int j = 0; j < J; ++j) {
            float4 v = xr[j * 64 + l];
            *(float4*)&xs[j * 256 + l * 4] = v;
            m = fmaxf(m, fmaxf(fmaxf(fabsf(v.x), fabsf(v.y)),
                               fmaxf(fabsf(v.z), fabsf(v.w))));
        }
#pragma unroll
        for (int d = 1; d < 64; d <<= 1) m = fmaxf(m, __shfl_xor(m, d));
        const float r = (m > 0.f) ? 127.f / m : 0.f;
        if (l == 0) scales[row] = m / 16129.f;       // rowmax / 127^2
        // tiled dest: row block (row>>4), within-block row (row&15)
        int8_t* orow_ = xq + (size_t)(row >> 4) * KB + (row & 15) * 64;
        for (int j = 0; j < J; ++j) {
            float4 v = *(const float4*)&xs[j * 256 + l * 4];
            int q0 = (int)rintf(v.x * r), q1 = (int)rintf(v.y * r);
            int q2 = (int)rintf(v.z * r), q3 = (int)rintf(v.w * r);
            uint32_t u = (uint32_t)(q0 & 255) | ((uint32_t)(q1 & 255) << 8) |
                         ((uint32_t)(q2 & 255) << 16) | ((uint32_t)(q3 & 255) << 24);
            // k = j*256 + l*4 -> k-tile j*4 + (l>>4), in-tile byte (l&15)*4
            *(uint32_t*)(orow_ + (size_t)(j * 4 + (l >> 4)) * 1024 + (l & 15) * 4) = u;
        }
    } else {
        // ---- W path: 64(k) x 64(n) tile -> Wq tiled ----
        int8_t* tq = (int8_t*)smem;                  // [64][72] i8
        const int wb = blockIdx.x - xblocks;
        const int gw = DOUT >> 6;
        const int c0 = (wb % gw) * 64;               // n base
        const int r0 = (wb / gw) * 64;               // k base
        const int kl = tid >> 4;                     // 0..15
        const int nc = (tid & 15) * 4;               // 0..60
#pragma unroll
        for (int i = 0; i < 4; ++i) {
            int k = r0 + kl + i * 16;
            float4 wv = *(const float4*)&W[(size_t)k * DOUT + c0 + nc];
            tq[(nc + 0) * 72 + kl + i * 16] = (int8_t)rintf(pwb_clip(wv.x) * 127.f);
            tq[(nc + 1) * 72 + kl + i * 16] = (int8_t)rintf(pwb_clip(wv.y) * 127.f);
            tq[(nc + 2) * 72 + kl + i * 16] = (int8_t)rintf(pwb_clip(wv.z) * 127.f);
            tq[(nc + 3) * 72 + kl + i * 16] = (int8_t)rintf(pwb_clip(wv.w) * 127.f);
        }
        __syncthreads();
        const int nl = tid >> 2, cc = (tid & 3) * 16;
        uint4 u;
        u.x = *(const uint32_t*)&tq[nl * 72 + cc + 0];
        u.y = *(const uint32_t*)&tq[nl * 72 + cc + 4];
        u.z = *(const uint32_t*)&tq[nl * 72 + cc + 8];
        u.w = *(const uint32_t*)&tq[nl * 72 + cc + 12];
        const int n = c0 + nl;
        *(uint4*)(Wq + (size_t)(n >> 4) * KB +
                  (size_t)(r0 >> 6) * 1024 + (n & 15) * 64 + cc) = u;
    }
}

// ================= main GEMM (i8, B from global) — R8 + A-swizzle =============
// C[M][N] = relu( (A x B^T) * scales[row] + q(b)[col] )
__global__ __launch_bounds__(256, 2) void pwb_gemmq(
    const int8_t* __restrict__ A,    // xq tiled [M/16][K/64][16][64]
    const int8_t* __restrict__ Bt,   // Wq tiled [N/16][K/64][16][64]
    const float* __restrict__ scales,// [M] rowmax/127^2
    const float* __restrict__ b,     // [N] raw bias (quantized inline)
    float* __restrict__ C,           // [M][N] f32
    int M, int N, int K, int GN, int nwg) {
    __shared__ __align__(16) int8_t lA[4][BM * BK];  // 4 x 8KB

    const int tid = threadIdx.x;
    const int w   = tid >> 6;     // 0..3
    const int l   = tid & 63;
    const int lr  = l & 15;
    const int lk  = l >> 4;       // 0..3

    // bijective XCD swizzle (m204)
    const int bid = blockIdx.x;
    const int q = nwg >> 3, r = nwg & 7;
    const int xcd = bid & 7, lin = bid >> 3;
    const int wgid = (xcd < r ? xcd * (q + 1) : r * (q + 1) + (xcd - r) * q) + lin;
    const int tm = wgid / GN, tn = wgid % GN;
    const size_t brow = (size_t)tm * BM, bcol = (size_t)tn * BN;

    const int wm = (w >> 1) * 64;   // wave M offset
    const int wn = (w & 1) * 64;    // wave N offset

    const int KT = K >> 6;                 // number of K-tiles
    const size_t KB = (size_t)KT << 10;    // bytes per 16-row block-row

    // A staging: thread copies chunk s = tid + 256*i (16B); m-block s>>6,
    // in-block chunk c = s&63 (row rr=c>>2, slot sl=c&3). LDS dest LINEAR
    // (tid*16); GLOBAL source chunk pre-swizzled: slot sl holds global chunk
    // sl^((rr>>1)&3)  [bank-spread involution; read applies the same].
    const int8_t* gA[2];
#pragma unroll
    for (int i = 0; i < 2; ++i) {
        int s = tid + 256 * i;
        int c = s & 63, rr = c >> 2, sl = c & 3;
        int gc = rr * 4 + (sl ^ ((rr >> 1) & 3));
        gA[i] = A + (size_t)((brow >> 4) + (s >> 6)) * KB + gc * 16;
    }
    // B frag pointer: lane lr=row-in-block, lk=16B chunk; frag nj adds nj blocks
    const int8_t* pB = Bt + (size_t)((bcol + wn) >> 4) * KB + lr * 64 + lk * 16;
    // A frag ds_read base: same XOR involution on the k-chunk slot
    const int offA = (wm >> 4) * 1024 + lr * 64 + ((lk ^ ((lr >> 1) & 3)) << 4);

    i32x4 acc[4][4] = {};
    i32x4 bS0[4], bS1[4], afr[4];

#define STAGE(buf, t)                                                   \
    gl16(gA[0] + (size_t)(t) * 1024, &lA[buf][tid * 16]);               \
    gl16(gA[1] + (size_t)(t) * 1024, &lA[buf][(tid + 256) * 16]);

#define LOADB(set, t)                                                   \
    _Pragma("unroll") for (int nj = 0; nj < 4; ++nj)                    \
        set[nj] = *(const i32x4*)(pB + (size_t)nj * KB + (size_t)(t) * 1024);

#define LOADA(buf)                                                      \
    _Pragma("unroll") for (int mi = 0; mi < 4; ++mi)                    \
        afr[mi] = *(const i32x4*)&lA[buf][offA + mi * 1024];

#define MFMA16(fb)                                                      \
    __builtin_amdgcn_s_setprio(1);                                      \
    _Pragma("unroll") for (int mi = 0; mi < 4; ++mi)                    \
    _Pragma("unroll") for (int nj = 0; nj < 4; ++nj)                    \
        acc[mi][nj] = __builtin_amdgcn_mfma_i32_16x16x64_i8(            \
            afr[mi], fb[nj], acc[mi][nj], 0, 0, 0);                     \
    __builtin_amdgcn_s_setprio(0);

    // ---- prologue: A0, B0, A1 in flight; wait A0+B0 ----
    STAGE(0, 0)
    LOADB(bS0, 0)
    STAGE(1, 1)
    WAIT_VM2
    BAR();

    const int T = KT;   // even, >= 4 (gated)
    for (int it = 0; it < (T - 2) / 2; ++it) {
        const int t0 = 2 * it;
        // tile t0: compute bS0; prefetch B(t0+1), stage A(t0+2)
        LOADB(bS1, t0 + 1)
        STAGE((t0 + 2) & 3, t0 + 2)
        LOADA(t0 & 3)
        WAIT_VM6            // retires B(t0) + A-stage(t0+1)
        BAR();
        MFMA16(bS0)
        // tile t0+1: compute bS1; prefetch B(t0+2), stage A(t0+3)
        LOADB(bS0, t0 + 2)
        STAGE((t0 + 3) & 3, t0 + 3)
        LOADA((t0 + 1) & 3)
        WAIT_VM6
        BAR();
        MFMA16(bS1)
    }
    // ---- tail: tiles T-2 (bS0), T-1 (bS1) ----
    LOADB(bS1, T - 1)
    LOADA((T - 2) & 3)
    WAIT_VM4                // retires B(T-2) + A-stage(T-1)
    BAR();
    MFMA16(bS0)
    WAIT_VM0                // B(T-1) in regs
    LOADA((T - 1) & 3)
    MFMA16(bS1)

    // ---- epilogue: y = acc * scales[row] + q(b)[col], relu.
    //      C/D layout: col = lane&15, row = (lane>>4)*4 + reg ----
    float bias[4];
#pragma unroll
    for (int nj = 0; nj < 4; ++nj) {
        float bv = b[bcol + wn + nj * 16 + lr];
        bias[nj] = rintf(pwb_clip(bv) * 127.f) * (1.f / 127.f);
    }

    const size_t orow = brow + wm + lk * 4;   // multiple of 4
    const size_t ocol = bcol + wn + lr;
    float4 scl[4];
#pragma unroll
    for (int mi = 0; mi < 4; ++mi)
        scl[mi] = *(const float4*)&scales[orow + mi * 16];

#pragma unroll
    for (int mi = 0; mi < 4; ++mi) {
        const float s0_ = scl[mi].x, s1_ = scl[mi].y, s2_ = scl[mi].z, s3_ = scl[mi].w;
#pragma unroll
        for (int nj = 0; nj < 4; ++nj) {
            float v0 = fmaf((float)acc[mi][nj][0], s0_, bias[nj]);
            float v1 = fmaf((float)acc[mi][nj][1], s1_, bias[nj]);
            float v2 = fmaf((float)acc[mi][nj][2], s2_, bias[nj]);
            float v3 = fmaf((float)acc[mi][nj][3], s3_, bias[nj]);
            float* cp = &C[(orow + mi * 16) * N + (ocol + nj * 16)];
            cp[0 * N] = fmaxf(v0, 0.f);
            cp[1 * N] = fmaxf(v1, 0.f);
            cp[2 * N] = fmaxf(v2, 0.f);
            cp[3 * N] = fmaxf(v3, 0.f);
        }
    }
#undef STAGE
#undef LOADB
#undef LOADA
#undef MFMA16
}

// ---- fallback (any shape): fp32, on-the-fly quantize ----
__global__ void pwb_fallback(const float* __restrict__ x, const float* __restrict__ W,
                             const float* __restrict__ b, float* __restrict__ out,
                             int M, int N, int K) {
    __shared__ float sA[16][17];
    __shared__ float sB[16][17];
    int tx = threadIdx.x, ty = threadIdx.y;
    int row = blockIdx.y * 16 + ty;
    int col = blockIdx.x * 16 + tx;
    float acc = 0.f;
    for (int kt = 0; kt < K; kt += 16) {
        sA[ty][tx] = (row < M && kt + tx < K) ? x[(size_t)row * K + kt + tx] : 0.f;
        float w = (kt + ty < K && col < N) ? W[(size_t)(kt + ty) * N + col] : 0.f;
        sB[ty][tx] = rintf(pwb_clip(w) * 127.f) * (1.f / 127.f);
        __syncthreads();
#pragma unroll
        for (int kk = 0; kk < 16; ++kk) acc += sA[ty][kk] * sB[kk][tx];
        __syncthreads();
    }
    if (row < M && col < N) {
        float v = acc + rintf(pwb_clip(b[col]) * 127.f) * (1.f / 127.f);
        out[(size_t)row * N + col] = fmaxf(v, 0.f);
    }
}

extern "C" void kernel_launch(void* const* d_in, const int* in_sizes, int n_in,
                              void* d_out, int out_size, void* d_ws, size_t ws_size,
                              hipStream_t stream) {
    const float* x = (const float*)d_in[0];
    const float* W = (const float*)d_in[1];
    const float* b = (const float*)d_in[2];
    float* out = (float*)d_out;

    const int DOUT = in_sizes[2];
    const int DIN  = in_sizes[1] / DOUT;
    const int M    = in_sizes[0] / DIN;

    size_t need = (size_t)M * DIN + (size_t)DIN * DOUT + (size_t)M * 4;
    const int T = DIN / 64;
    bool fast = (M % BM == 0) && (M % 4 == 0) && (DOUT % BN == 0) &&
                (DIN % 256 == 0) && (DIN <= 2048) && (T >= 4) && ((T & 1) == 0) &&
                (ws_size >= need);

    if (fast) {
        int8_t* xq = (int8_t*)d_ws;                       // tiled [M/16][K/64][16][64]
        int8_t* Wq = xq + (size_t)M * DIN;                // tiled [N/16][K/64][16][64]
        float* scales = (float*)(Wq + (size_t)DIN * DOUT);// [M] f32

        const int xblocks = M / 4;
        const int wblocks = (DIN / 64) * (DOUT / 64);
        pwb_prep<<<xblocks + wblocks, 256, 0, stream>>>(x, W, xq, Wq, scales,
                                                        DIN, DOUT, xblocks);

        const int GM = M / BM, GN = DOUT / BN, nwg = GM * GN;
        pwb_gemmq<<<nwg, 256, 0, stream>>>(xq, Wq, scales, b, out, M, DOUT, DIN, GN, nwg);
    } else {
        dim3 g((DOUT + 15) / 16, (M + 15) / 16), blk(16, 16);
        pwb_fallback<<<g, blk, 0, stream>>>(x, W, b, out, M, DOUT, DIN);
    }
}

// Round 15
// 35.870 us; speedup vs baseline: 1.3813x; 1.1285x over previous
//
#include <hip/hip_runtime.h>
#include <hip/hip_bf16.h>
#include <stdint.h>

// PWB linear layer: out = relu(x @ q(W) + q(b)), q = round(clip(t,-1,1)*127)/127
// R15: R14 schedule byte-identical; ONLY the wave->subtile mapping changes:
// 2Mx2N (64x64/wave, B frags duplicated across wave pairs) -> 1Mx4N
// (128x32/wave, each wave owns a distinct 32-col B slice -> ZERO B
// duplication; per-CU L2 reads 48->32 KB/tile). A shared by all 4 waves via
// LDS (reads 2x, LDS has 3x headroom). acc[8][2], afr[8], bS[2]x2 ~ 124 VGPR
// -> 2 blocks/CU kept. vmcnt ledger (2 B-loads + 2 stages/phase): prologue
// vm2, steady vm4, tail vm2->vm0.
// Layouts: xq[M/16][K/64][16][64] i8, Wq[N/16][K/64][16][64] i8.

typedef __attribute__((ext_vector_type(4))) int i32x4;

#define BM 128
#define BN 128
#define BK 64

__device__ __forceinline__ float pwb_clip(float w) {
    return fminf(fmaxf(w, -1.f), 1.f);
}

__device__ __forceinline__ void gl16(const int8_t* g, int8_t* l) {
    __builtin_amdgcn_global_load_lds(
        (const __attribute__((address_space(1))) void*)(g),
        (__attribute__((address_space(3))) void*)(l),
        16, 0, 0);
}

#define WAIT_VM4   asm volatile("s_waitcnt vmcnt(4)" ::: "memory");
#define WAIT_VM2   asm volatile("s_waitcnt vmcnt(2)" ::: "memory");
#define WAIT_VM0   asm volatile("s_waitcnt vmcnt(0)" ::: "memory");
#define BAR()      __builtin_amdgcn_s_barrier();

// ---- merged pre-pass (verbatim R8) ----
__global__ void pwb_prep(const float* __restrict__ x, const float* __restrict__ W,
                         int8_t* __restrict__ xq, int8_t* __restrict__ Wq,
                         float* __restrict__ scales, int DIN, int DOUT, int xblocks) {
    __shared__ __align__(16) float smem[4 * 2048];   // 32KB
    const int tid = threadIdx.x;
    const size_t KB = (size_t)(DIN >> 6) << 10;      // bytes per 16-row block-row

    if ((int)blockIdx.x < xblocks) {
        const int wv = tid >> 6, l = tid & 63;
        const int row = blockIdx.x * 4 + wv;
        const float4* xr = (const float4*)(x + (size_t)row * DIN);
        float* xs = smem + wv * 2048;
        const int J = DIN >> 8;
        float m = 0.f;
        for (int j = 0; j < J; ++j) {
            float4 v = xr[j * 64 + l];
            *(float4*)&xs[j * 256 + l * 4] = v;
            m = fmaxf(m, fmaxf(fmaxf(fabsf(v.x), fabsf(v.y)),
                               fmaxf(fabsf(v.z), fabsf(v.w))));
        }
#pragma unroll
        for (int d = 1; d < 64; d <<= 1) m = fmaxf(m, __shfl_xor(m, d));
        const float r = (m > 0.f) ? 127.f / m : 0.f;
        if (l == 0) scales[row] = m / 16129.f;       // rowmax / 127^2
        int8_t* orow_ = xq + (size_t)(row >> 4) * KB + (row & 15) * 64;
        for (int j = 0; j < J; ++j) {
            float4 v = *(const float4*)&xs[j * 256 + l * 4];
            int q0 = (int)rintf(v.x * r), q1 = (int)rintf(v.y * r);
            int q2 = (int)rintf(v.z * r), q3 = (int)rintf(v.w * r);
            uint32_t u = (uint32_t)(q0 & 255) | ((uint32_t)(q1 & 255) << 8) |
                         ((uint32_t)(q2 & 255) << 16) | ((uint32_t)(q3 & 255) << 24);
            *(uint32_t*)(orow_ + (size_t)(j * 4 + (l >> 4)) * 1024 + (l & 15) * 4) = u;
        }
    } else {
        int8_t* tq = (int8_t*)smem;                  // [64][72] i8
        const int wb = blockIdx.x - xblocks;
        const int gw = DOUT >> 6;
        const int c0 = (wb % gw) * 64;               // n base
        const int r0 = (wb / gw) * 64;               // k base
        const int kl = tid >> 4;
        const int nc = (tid & 15) * 4;
#pragma unroll
        for (int i = 0; i < 4; ++i) {
            int k = r0 + kl + i * 16;
            float4 wv = *(const float4*)&W[(size_t)k * DOUT + c0 + nc];
            tq[(nc + 0) * 72 + kl + i * 16] = (int8_t)rintf(pwb_clip(wv.x) * 127.f);
            tq[(nc + 1) * 72 + kl + i * 16] = (int8_t)rintf(pwb_clip(wv.y) * 127.f);
            tq[(nc + 2) * 72 + kl + i * 16] = (int8_t)rintf(pwb_clip(wv.z) * 127.f);
            tq[(nc + 3) * 72 + kl + i * 16] = (int8_t)rintf(pwb_clip(wv.w) * 127.f);
        }
        __syncthreads();
        const int nl = tid >> 2, cc = (tid & 3) * 16;
        uint4 u;
        u.x = *(const uint32_t*)&tq[nl * 72 + cc + 0];
        u.y = *(const uint32_t*)&tq[nl * 72 + cc + 4];
        u.z = *(const uint32_t*)&tq[nl * 72 + cc + 8];
        u.w = *(const uint32_t*)&tq[nl * 72 + cc + 12];
        const int n = c0 + nl;
        *(uint4*)(Wq + (size_t)(n >> 4) * KB +
                  (size_t)(r0 >> 6) * 1024 + (n & 15) * 64 + cc) = u;
    }
}

// ============ main GEMM (i8, B from global, 1Mx4N wave mapping) ============
// C[M][N] = relu( (A x B^T) * scales[row] + q(b)[col] )
__global__ __launch_bounds__(256, 2) void pwb_gemmq(
    const int8_t* __restrict__ A,    // xq tiled [M/16][K/64][16][64]
    const int8_t* __restrict__ Bt,   // Wq tiled [N/16][K/64][16][64]
    const float* __restrict__ scales,// [M] rowmax/127^2
    const float* __restrict__ b,     // [N] raw bias (quantized inline)
    float* __restrict__ C,           // [M][N] f32
    int M, int N, int K, int GN, int nwg) {
    __shared__ __align__(16) int8_t lA[4][BM * BK];  // 4 x 8KB

    const int tid = threadIdx.x;
    const int w   = tid >> 6;     // 0..3  (wave n-slice: cols w*32..w*32+31)
    const int l   = tid & 63;
    const int lr  = l & 15;
    const int lk  = l >> 4;       // 0..3

    // bijective XCD swizzle (m204)
    const int bid = blockIdx.x;
    const int q = nwg >> 3, r = nwg & 7;
    const int xcd = bid & 7, lin = bid >> 3;
    const int wgid = (xcd < r ? xcd * (q + 1) : r * (q + 1) + (xcd - r) * q) + lin;
    const int tm = wgid / GN, tn = wgid % GN;
    const size_t brow = (size_t)tm * BM, bcol = (size_t)tn * BN;

    const int KT = K >> 6;                 // number of K-tiles
    const size_t KB = (size_t)KT << 10;    // bytes per 16-row block-row

    // A staging (verbatim R14): thread covers chunk s = tid + 256*i (16B);
    // LDS dest LINEAR; global source chunk pre-swizzled sl^((rr>>1)&3).
    const int8_t* gA[2];
#pragma unroll
    for (int i = 0; i < 2; ++i) {
        int s = tid + 256 * i;
        int c = s & 63, rr = c >> 2, sl = c & 3;
        int gc = rr * 4 + (sl ^ ((rr >> 1) & 3));
        gA[i] = A + (size_t)((brow >> 4) + (s >> 6)) * KB + gc * 16;
    }
    // B frag pointer: wave n-base = w*32; frag nj (0..1) adds nj block-rows
    const int8_t* pB = Bt + (size_t)((bcol >> 4) + w * 2) * KB + lr * 64 + lk * 16;
    // A frag ds_read base: frag mi (0..7) at mi*1024; XOR involution on slot
    const int offA = lr * 64 + ((lk ^ ((lr >> 1) & 3)) << 4);

    i32x4 acc[8][2] = {};
    i32x4 bS0[2], bS1[2], afr[8];

#define STAGE(buf, t)                                                   \
    gl16(gA[0] + (size_t)(t) * 1024, &lA[buf][tid * 16]);               \
    gl16(gA[1] + (size_t)(t) * 1024, &lA[buf][(tid + 256) * 16]);

#define LOADB(set, t)                                                   \
    _Pragma("unroll") for (int nj = 0; nj < 2; ++nj)                    \
        set[nj] = *(const i32x4*)(pB + (size_t)nj * KB + (size_t)(t) * 1024);

#define LOADA(buf)                                                      \
    _Pragma("unroll") for (int mi = 0; mi < 8; ++mi)                    \
        afr[mi] = *(const i32x4*)&lA[buf][offA + mi * 1024];

#define MFMA16(fb)                                                      \
    __builtin_amdgcn_s_setprio(1);                                      \
    _Pragma("unroll") for (int mi = 0; mi < 8; ++mi)                    \
    _Pragma("unroll") for (int nj = 0; nj < 2; ++nj)                    \
        acc[mi][nj] = __builtin_amdgcn_mfma_i32_16x16x64_i8(            \
            afr[mi], fb[nj], acc[mi][nj], 0, 0, 0);                     \
    __builtin_amdgcn_s_setprio(0);

    // ---- prologue: stage(0)[2] B(0)[2] stage(1)[2] -> retire 4, keep stage(1)
    STAGE(0, 0)
    LOADB(bS0, 0)
    STAGE(1, 1)
    WAIT_VM2
    BAR();

    const int T = KT;   // even, >= 4 (gated)
    for (int it = 0; it < (T - 2) / 2; ++it) {
        const int t0 = 2 * it;
        // phase even: compute bS0; issue B(t0+1)[2], stage(t0+2)[2]
        LOADB(bS1, t0 + 1)
        STAGE((t0 + 2) & 3, t0 + 2)
        LOADA(t0 & 3)
        WAIT_VM4            // retires B(t0)/prev-phase issues; keeps newest 4
        BAR();
        MFMA16(bS0)
        // phase odd: compute bS1; issue B(t0+2)[2], stage(t0+3)[2]
        LOADB(bS0, t0 + 2)
        STAGE((t0 + 3) & 3, t0 + 3)
        LOADA((t0 + 1) & 3)
        WAIT_VM4
        BAR();
        MFMA16(bS1)
    }
    // ---- tail: tiles T-2 (bS0), T-1 (bS1) ----
    LOADB(bS1, T - 1)
    LOADA((T - 2) & 3)
    WAIT_VM2                // retires B(T-2) + stage(T-1); keeps B(T-1)
    BAR();
    MFMA16(bS0)
    WAIT_VM0                // B(T-1) in regs
    LOADA((T - 1) & 3)
    MFMA16(bS1)

    // ---- epilogue: y = acc * scales[row] + q(b)[col], relu.
    //      C/D layout: col = lane&15, row = (lane>>4)*4 + reg ----
    float bias[2];
#pragma unroll
    for (int nj = 0; nj < 2; ++nj) {
        float bv = b[bcol + w * 32 + nj * 16 + lr];
        bias[nj] = rintf(pwb_clip(bv) * 127.f) * (1.f / 127.f);
    }

    const size_t orow = brow + lk * 4;        // + mi*16 per frag
    const size_t ocol = bcol + w * 32 + lr;
#pragma unroll
    for (int mi = 0; mi < 8; ++mi) {
        float4 scl = *(const float4*)&scales[orow + mi * 16];
#pragma unroll
        for (int nj = 0; nj < 2; ++nj) {
            float v0 = fmaf((float)acc[mi][nj][0], scl.x, bias[nj]);
            float v1 = fmaf((float)acc[mi][nj][1], scl.y, bias[nj]);
            float v2 = fmaf((float)acc[mi][nj][2], scl.z, bias[nj]);
            float v3 = fmaf((float)acc[mi][nj][3], scl.w, bias[nj]);
            float* cp = &C[(orow + mi * 16) * N + (ocol + nj * 16)];
            cp[0 * N] = fmaxf(v0, 0.f);
            cp[1 * N] = fmaxf(v1, 0.f);
            cp[2 * N] = fmaxf(v2, 0.f);
            cp[3 * N] = fmaxf(v3, 0.f);
        }
    }
#undef STAGE
#undef LOADB
#undef LOADA
#undef MFMA16
}

// ---- fallback (any shape): fp32, on-the-fly quantize ----
__global__ void pwb_fallback(const float* __restrict__ x, const float* __restrict__ W,
                             const float* __restrict__ b, float* __restrict__ out,
                             int M, int N, int K) {
    __shared__ float sA[16][17];
    __shared__ float sB[16][17];
    int tx = threadIdx.x, ty = threadIdx.y;
    int row = blockIdx.y * 16 + ty;
    int col = blockIdx.x * 16 + tx;
    float acc = 0.f;
    for (int kt = 0; kt < K; kt += 16) {
        sA[ty][tx] = (row < M && kt + tx < K) ? x[(size_t)row * K + kt + tx] : 0.f;
        float w = (kt + ty < K && col < N) ? W[(size_t)(kt + ty) * N + col] : 0.f;
        sB[ty][tx] = rintf(pwb_clip(w) * 127.f) * (1.f / 127.f);
        __syncthreads();
#pragma unroll
        for (int kk = 0; kk < 16; ++kk) acc += sA[ty][kk] * sB[kk][tx];
        __syncthreads();
    }
    if (row < M && col < N) {
        float v = acc + rintf(pwb_clip(b[col]) * 127.f) * (1.f / 127.f);
        out[(size_t)row * N + col] = fmaxf(v, 0.f);
    }
}

extern "C" void kernel_launch(void* const* d_in, const int* in_sizes, int n_in,
                              void* d_out, int out_size, void* d_ws, size_t ws_size,
                              hipStream_t stream) {
    const float* x = (const float*)d_in[0];
    const float* W = (const float*)d_in[1];
    const float* b = (const float*)d_in[2];
    float* out = (float*)d_out;

    const int DOUT = in_sizes[2];
    const int DIN  = in_sizes[1] / DOUT;
    const int M    = in_sizes[0] / DIN;

    size_t need = (size_t)M * DIN + (size_t)DIN * DOUT + (size_t)M * 4;
    const int T = DIN / 64;
    bool fast = (M % BM == 0) && (M % 4 == 0) && (DOUT % BN == 0) &&
                (DIN % 256 == 0) && (DIN <= 2048) && (T >= 4) && ((T & 1) == 0) &&
                (ws_size >= need);

    if (fast) {
        int8_t* xq = (int8_t*)d_ws;                       // tiled [M/16][K/64][16][64]
        int8_t* Wq = xq + (size_t)M * DIN;                // tiled [N/16][K/64][16][64]
        float* scales = (float*)(Wq + (size_t)DIN * DOUT);// [M] f32

        const int xblocks = M / 4;
        const int wblocks = (DIN / 64) * (DOUT / 64);
        pwb_prep<<<xblocks + wblocks, 256, 0, stream>>>(x, W, xq, Wq, scales,
                                                        DIN, DOUT, xblocks);

        const int GM = M / BM, GN = DOUT / BN, nwg = GM * GN;
        pwb_gemmq<<<nwg, 256, 0, stream>>>(xq, Wq, scales, b, out, M, DOUT, DIN, GN, nwg);
    } else {
        dim3 g((DOUT + 15) / 16, (M + 15) / 16), blk(16, 16);
        pwb_fallback<<<g, blk, 0, stream>>>(x, W, b, out, M, DOUT, DIN);
    }
}